// Round 10
// baseline (465.739 us; speedup 1.0000x reference)
//
#include <hip/hip_runtime.h>
#include <stdint.h>
#include <math.h>

#define M_DIM 8192
#define N_DIM 4096
#define K_DIM 4096
#define BITWIDTH 7

#define BM 256
#define BN 128
#define NK 128    // 32-byte kk-steps over K

using i32x4  = __attribute__((ext_vector_type(4)))  int;
using i32x16 = __attribute__((ext_vector_type(16))) int;

#define FENCE asm volatile("" ::: "memory")

// ---------------------------------------------------------------------------
// Combined pack, one launch: BOTH tensors -> MFMA-fragment-blocked int8.
//   blocks [0, 8192):     A (8192x4096)  -> a8p
//   blocks [8192, 12288): B (4096x4096)  -> w8p
//
// Fragment-blocked layout (R4-verified on A): for row-block rb (32 rows)
// and K-block kb (32 bytes), a 1 KB block at ((rb*128 + kb) * 1024); lane
// L's 16 bytes at offset L*16: src[rb*32 + (L&31)][kb*32 + (L>>5)*16 + 0..15].
// This is byte-identical to the operand image the verified MFMA fragment
// reads consume, so GEMM loads both operands as lane-linear coalesced
// global_load_dwordx4 -- no LDS tier needed at all.
// ---------------------------------------------------------------------------
__global__ __launch_bounds__(256) void pack_both_kernel(
        const int* __restrict__ act, const int* __restrict__ wt,
        uint32_t* __restrict__ a8p, uint32_t* __restrict__ w8p,
        int* __restrict__ maxabs) {
    if (blockIdx.x == 0 && threadIdx.x == 0) *maxabs = 0;

    const int* src;
    uint32_t* dst;
    int t2;
    if (blockIdx.x < 8192) { src = act; dst = a8p; t2 = blockIdx.x * 256 + threadIdx.x; }
    else                   { src = wt;  dst = w8p; t2 = (blockIdx.x - 8192) * 256 + threadIdx.x; }

    const int L  = t2 & 63;
    const int kb = (t2 >> 6) & 127;           // K/32 = 128 blocks
    const int rb = t2 >> 13;                  // row-block (A: 0..255, B: 0..127)
    const size_t s = (size_t)(rb * 32 + (L & 31)) * K_DIM + kb * 32 + (L >> 5) * 16;
    const int4* sp = (const int4*)(src + s);
    uint32_t w[4];
#pragma unroll
    for (int q = 0; q < 4; ++q) {
        int4 v = sp[q];
        w[q] = (uint32_t)(v.x & 0xFF) | ((uint32_t)(v.y & 0xFF) << 8)
             | ((uint32_t)(v.z & 0xFF) << 16) | ((uint32_t)(v.w & 0xFF) << 24);
    }
    ((uint4*)dst)[t2] = make_uint4(w[0], w[1], w[2], w[3]);
}

// load one kk-step's 2 A fragments (coalesced dwordx4 from packed layout)
__device__ __forceinline__ void load_af(i32x4 (&d)[2], const int8_t* aBase,
                                        int ks) {
#pragma unroll
    for (int i = 0; i < 2; ++i)
        d[i] = *(const i32x4*)(aBase + (size_t)((i * 128 + ks) << 10));
}

// load one kk-step's 4 B fragments (coalesced dwordx4 from packed layout)
__device__ __forceinline__ void load_bfg(i32x4 (&d)[4], const int8_t* bBase,
                                         int ks) {
#pragma unroll
    for (int j = 0; j < 4; ++j)
        d[j] = *(const i32x4*)(bBase + (size_t)((j * 128 + ks) << 10));
}

// one kk-step: 8 MFMAs, all operands pre-loaded (no memory ops inside)
__device__ __forceinline__ void kkstep(const i32x4 (&a)[2], const i32x4 (&b)[4],
                                       i32x16 (&acc)[2][4]) {
#pragma unroll
    for (int i = 0; i < 2; ++i)
#pragma unroll
        for (int j = 0; j < 4; ++j)
            acc[i][j] = __builtin_amdgcn_mfma_i32_32x32x32_i8(
                a[i], b[j], acc[i][j], 0, 0, 0);
}

// ---------------------------------------------------------------------------
// i8 GEMM, R9: ZERO-LDS pure-register streaming GEMM.
//
// Both operands read directly from fragment-packed global layouts as
// lane-linear global_load_dwordx4, register-double-buffered (static E/O
// parity, rule-#20-safe) at kk granularity. NO LDS tier, NO staging, NO
// in-loop barriers: waves free-run, so the VMEM pipe (loads, ~500
// cyc/CU/phase) and the MFMA pipe (585 cyc/SIMD/phase) overlap without
// barrier-forced serialization; 2-blocks/CU anti-phase naturally.
//
// Locality: B fragments are wave-shared within a block -> L1-deduped
// (16 KB/phase); A rows per-wave distinct. Default bx-fast dispatch gives
// each XCD {1 MB A row-panel + 4 x 512 KB B col-panels} ~ 3 MB < 4 MB L2.
//
// Removed vs R8: 8.39e6 LDS bank-conflict cycles, XOR-swizzle VALU ops,
// 256 barrier-pairs/block, all gload_lds staging.
// ---------------------------------------------------------------------------
__global__ __launch_bounds__(256, 2) void gemm_i8(
        const int8_t* __restrict__ A8p, const int8_t* __restrict__ B8p,
        int* __restrict__ C, int* __restrict__ maxabs) {
    __shared__ int wmaxs[4];

    const int tid  = threadIdx.x;
    const int wave = tid >> 6;
    const int lane = tid & 63;
    const int fr   = lane & 31;
    const int hl   = lane >> 5;

    const int row0 = blockIdx.y * BM;
    const int col0 = blockIdx.x * BN;
    const int wm   = wave * 64;        // wave row offset (4M x 1N grid)

    i32x16 acc[2][4];
#pragma unroll
    for (int i = 0; i < 2; ++i)
#pragma unroll
        for (int j = 0; j < 4; ++j)
            acc[i][j] = (i32x16)(0);

    // fragment base pointers (packed global, lane-linear)
    const int8_t* aBase = A8p + ((size_t)((row0 >> 5) + wave * 2) << 17)
                              + (size_t)lane * 16;
    const int8_t* bBase = B8p + ((size_t)(col0 >> 5) << 17)
                              + (size_t)lane * 16;

    i32x4 afE[2], afO[2], bfE[4], bfO[4];

    // prologue: fragments for kk-step 0
    load_af(afE, aBase, 0);
    load_bfg(bfE, bBase, 0);

    // main loop: 128 kk-steps, unroll 2 (E/O parity), distance-1 prefetch
    for (int ks = 0; ks < NK; ks += 2) {
        load_af(afO, aBase, ks + 1);          // ks+1 <= 127 always
        load_bfg(bfO, bBase, ks + 1);
        FENCE;
        kkstep(afE, bfE, acc);
        const int nxt = (ks + 2 < NK) ? ks + 2 : NK - 1;   // clamped tail
        load_af(afE, aBase, nxt);
        load_bfg(bfE, bBase, nxt);
        FENCE;
        kkstep(afO, bfO, acc);
    }

    // epilogue: 32x32 C/D layout: col = lane&31,
    // row = (reg&3) + 8*(reg>>2) + 4*(lane>>5)   [m74/m101, dtype-independent]
    int mymax = 0;
    const int ccol = fr;
    const int rbase = hl << 2;
#pragma unroll
    for (int i = 0; i < 2; ++i) {
#pragma unroll
        for (int j = 0; j < 4; ++j) {
            int* p = C + (size_t)(row0 + wm + i * 32) * N_DIM
                       + (col0 + j * 32 + ccol);
#pragma unroll
            for (int r = 0; r < 16; ++r) {
                int row = (r & 3) + 8 * (r >> 2) + rbase;
                int v = acc[i][j][r];
                p[(size_t)row * N_DIM] = v;
                int a = v < 0 ? -v : v;
                mymax = a > mymax ? a : mymax;
            }
        }
    }

    // wave-reduce max, then one atomic per block
#pragma unroll
    for (int off = 32; off > 0; off >>= 1) {
        int o = __shfl_down(mymax, off, 64);
        mymax = o > mymax ? o : mymax;
    }
    if (lane == 0) wmaxs[wave] = mymax;
    __syncthreads();
    if (tid == 0) {
        int bmx = wmaxs[0];
        for (int w = 1; w < 4; ++w) bmx = wmaxs[w] > bmx ? wmaxs[w] : bmx;
        atomicMax(maxabs, bmx);
    }
}

// ---------------------------------------------------------------------------
// Pseudo-stochastic shift, faithful to PstoShiftInt32 (all-integer, exact).
// ---------------------------------------------------------------------------
__device__ __forceinline__ int psto(int x, int eff) {
    if (eff > 0) {
        int rt   = x >> eff;                 // floor divide by 2^eff
        int prob = x & ((1 << eff) - 1);     // non-negative floor remainder
        int h    = eff >> 1;
        int qp   = prob >> h;
        int prn  = (prob & ((1 << h) - 1)) << (eff & 1);
        int sgn  = (x > 0) - (x < 0);
        int r    = rt + ((qp <= prn) ? 0 : sgn);
        r = r < -127 ? -127 : r;
        r = r > 127 ? 127 : r;
        return r;
    }
    return (int)(int8_t)x;                   // wrapping int8 cast, as in torch
}

// ---------------------------------------------------------------------------
// In-place: read int32 acc from C, write int32 quantized value back.
// ---------------------------------------------------------------------------
__global__ __launch_bounds__(256) void finalize_kernel(int* __restrict__ C,
        const int* __restrict__ maxabs,
        const int* __restrict__ exp_in,
        const int* __restrict__ wexp) {
    const int m = *maxabs;
    int bw = 0;
    if (m != 0) bw = (int)ceilf(log2f((float)m));   // float32 path, as reference
    const int shift = bw - BITWIDTH;
    const int eff = (shift > 1) ? shift : ((shift == 1) ? 2 : 0);

    const size_t idx = ((size_t)blockIdx.x * blockDim.x + threadIdx.x) * 8;
    int4 v0 = *(const int4*)(C + idx);
    int4 v1 = *(const int4*)(C + idx + 4);
    int4 o0, o1;
    o0.x = psto(v0.x, eff); o0.y = psto(v0.y, eff);
    o0.z = psto(v0.z, eff); o0.w = psto(v0.w, eff);
    o1.x = psto(v1.x, eff); o1.y = psto(v1.y, eff);
    o1.z = psto(v1.z, eff); o1.w = psto(v1.w, eff);
    *(int4*)(C + idx) = o0;
    *(int4*)(C + idx + 4) = o1;

    if (idx == 0) {
        C[(size_t)M_DIM * N_DIM] = (int)(int8_t)(exp_in[0] + wexp[0] + eff);
    }
}

// ---------------------------------------------------------------------------
extern "C" void kernel_launch(void* const* d_in, const int* in_sizes, int n_in,
                              void* d_out, int out_size, void* d_ws, size_t ws_size,
                              hipStream_t stream) {
    const int* act    = (const int*)d_in[0];
    const int* exp_in = (const int*)d_in[1];
    const int* wt     = (const int*)d_in[2];
    const int* wexp   = (const int*)d_in[3];

    int8_t* a8p    = (int8_t*)d_ws;                          // 32 MB (frag-packed)
    int8_t* w8p    = a8p + (size_t)M_DIM * K_DIM;            // 16 MB (frag-packed)
    int*    maxabs = (int*)(w8p + (size_t)N_DIM * K_DIM);    // 4 B

    // blocks [0,8192): A frag-pack; [8192,12288): B frag-pack
    pack_both_kernel<<<12288, 256, 0, stream>>>(
        act, wt, (uint32_t*)a8p, (uint32_t*)w8p, maxabs);

    int* C = (int*)d_out;    // acc staged in-place in d_out
    dim3 grid(N_DIM / BN, M_DIM / BM);
    gemm_i8<<<grid, 256, 0, stream>>>(a8p, w8p, C, maxabs);

    finalize_kernel<<<((size_t)M_DIM * N_DIM / 8) / 256, 256, 0, stream>>>(
        C, maxabs, exp_in, wexp);
}

// Round 11
// 432.472 us; speedup vs baseline: 1.0769x; 1.0769x over previous
//
#include <hip/hip_runtime.h>
#include <stdint.h>
#include <math.h>

#define M_DIM 8192
#define N_DIM 4096
#define K_DIM 4096
#define BITWIDTH 7

#define BM 256
#define BN 128
#define NT 32     // K-tiles of 128 bytes (4 kk-steps each)

using i32x4  = __attribute__((ext_vector_type(4)))  int;
using i32x16 = __attribute__((ext_vector_type(16))) int;

#define FENCE asm volatile("" ::: "memory")

// ---------------------------------------------------------------------------
// Combined pack, one launch: BOTH tensors -> MFMA-fragment-blocked int8.
//   blocks [0, 8192):     A (8192x4096)  -> a8p
//   blocks [8192, 12288): B (4096x4096)  -> w8p
//
// Fragment-blocked layout (A path R4-verified; B path R9-harness-verified):
// for row-block rb (32 rows) and K-block kb (32 bytes), a 1 KB block at
// ((rb*128 + kb) * 1024); lane L's 16 bytes at offset L*16:
// src[rb*32 + (L&31)][kb*32 + (L>>5)*16 + 0..15] -- byte-identical to the
// operand image the verified MFMA fragment reads consume.
// ---------------------------------------------------------------------------
__global__ __launch_bounds__(256) void pack_both_kernel(
        const int* __restrict__ act, const int* __restrict__ wt,
        uint32_t* __restrict__ a8p, uint32_t* __restrict__ w8p,
        int* __restrict__ maxabs) {
    if (blockIdx.x == 0 && threadIdx.x == 0) *maxabs = 0;

    const int* src;
    uint32_t* dst;
    int t2;
    if (blockIdx.x < 8192) { src = act; dst = a8p; t2 = blockIdx.x * 256 + threadIdx.x; }
    else                   { src = wt;  dst = w8p; t2 = (blockIdx.x - 8192) * 256 + threadIdx.x; }

    const int L  = t2 & 63;
    const int kb = (t2 >> 6) & 127;           // K/32 = 128 blocks
    const int rb = t2 >> 13;                  // row-block (A: 0..255, B: 0..127)
    const size_t s = (size_t)(rb * 32 + (L & 31)) * K_DIM + kb * 32 + (L >> 5) * 16;
    const int4* sp = (const int4*)(src + s);
    uint32_t w[4];
#pragma unroll
    for (int q = 0; q < 4; ++q) {
        int4 v = sp[q];
        w[q] = (uint32_t)(v.x & 0xFF) | ((uint32_t)(v.y & 0xFF) << 8)
             | ((uint32_t)(v.z & 0xFF) << 16) | ((uint32_t)(v.w & 0xFF) << 24);
    }
    ((uint4*)dst)[t2] = make_uint4(w[0], w[1], w[2], w[3]);
}

// ---------------------------------------------------------------------------
// async global->LDS, 16B per lane, LDS dest = wave-uniform base + lane*16
// ---------------------------------------------------------------------------
__device__ __forceinline__ void gload_lds16(const int8_t* g, int8_t* lds) {
    __builtin_amdgcn_global_load_lds(
        (__attribute__((address_space(1))) void*)g,
        (__attribute__((address_space(3))) void*)lds,
        16, 0, 0);
}

// load one kk-step's 2 A fragments (coalesced dwordx4 from packed layout)
__device__ __forceinline__ void load_af(i32x4 (&d)[2], const int8_t* aBase,
                                        int ks) {
#pragma unroll
    for (int i = 0; i < 2; ++i)
        d[i] = *(const i32x4*)(aBase + (size_t)((i * 128 + ks) << 10));
}

// load one kk-step's 4 B fragments from LDS: lane-linear (base incl. lane*16)
// + compile-time block offsets -> conflict-free sequential bank access.
__device__ __forceinline__ void load_bfl(i32x4 (&d)[4], const int8_t* bbuf,
                                         int ks) {
#pragma unroll
    for (int j = 0; j < 4; ++j)
        d[j] = *(const i32x4*)(bbuf + ((j * 4 + ks) << 10));
}

// one kk-step: 8 MFMAs, all operands pre-loaded (no memory ops inside)
__device__ __forceinline__ void kkstep(const i32x4 (&a)[2], const i32x4 (&b)[4],
                                       i32x16 (&acc)[2][4]) {
#pragma unroll
    for (int i = 0; i < 2; ++i)
#pragma unroll
        for (int j = 0; j < 4; ++j)
            acc[i][j] = __builtin_amdgcn_mfma_i32_32x32x32_i8(
                a[i], b[j], acc[i][j], 0, 0, 0);
}

// ---------------------------------------------------------------------------
// i8 GEMM, R10: R8's phase skeleton + fragment-packed B-LDS (conflict-free)
// + 2 phases/tile (16-MFMA clusters).
//
// Pipe assignment (isolated by R0/R8/R9 triple): A on VMEM (packed global,
// per-wave-distinct rows), B on LDS (wave-shared, separate lgkm pipe).
// B is staged from its PACKED layout: each 1 KB fragment block is a linear
// global->LDS DMA; reads are lane-linear ds_read_b128 with immediate
// offsets -> zero bank conflicts, zero swizzle arithmetic.
//
// Per tile t (2 phases):
//  ph0: ds bf(ks0,ks1) | af(ks2,ks3) | stage B(t+1) x4 (1KB blocks)
//       barrier; lgkm(0); prio1; 16 MFMA; prio0; barrier
//  ph1: ds bf(ks2,ks3) | af(t+1: ks0,ks1)
//       barrier; lgkm(0); prio1; 16 MFMA; prio0; vmcnt(4); barrier
// vmcnt audit (in-order): queue at ph1 end = [stage x4, af01(t+1) x4];
// vmcnt(4) retires exactly the staging (a full tile of cover vs ~900cyc
// HBM); af01 survives the barrier. The ph1 MFMA's compiler wait targets
// af2/af3 (issued BEFORE staging) so staging is never retired early.
// Ring-2 WAR: staging writes buf^1 while all tile-t reads (lgkm-drained
// pre-barrier) hit buf.
// ---------------------------------------------------------------------------
__global__ __launch_bounds__(256, 2) void gemm_i8(
        const int8_t* __restrict__ A8p, const int8_t* __restrict__ B8p,
        int* __restrict__ C, int* __restrict__ maxabs) {
    __shared__ __align__(16) int8_t Bs[2][16384];   // 2 x 16 KB ring
    __shared__ int wmaxs[4];
    int8_t* BsF = &Bs[0][0];

    const int tid  = threadIdx.x;
    const int wave = tid >> 6;
    const int lane = tid & 63;
    const int fr   = lane & 31;
    const int hl   = lane >> 5;

    const int row0 = blockIdx.y * BM;
    const int col0 = blockIdx.x * BN;
    const int wm   = wave * 64;        // wave row offset (4M x 1N grid)

    i32x16 acc[2][4];
#pragma unroll
    for (int i = 0; i < 2; ++i)
#pragma unroll
        for (int j = 0; j < 4; ++j)
            acc[i][j] = (i32x16)(0);

    // A fragments: packed global, per-wave-distinct rows
    const int8_t* aBase = A8p + ((size_t)((row0 >> 5) + wave * 2) << 17)
                              + (size_t)lane * 16;
    // B staging source: wave w owns fragment-row-block (col0/32 + w)
    const int8_t* bSrc  = B8p + ((size_t)((col0 >> 5) + wave) << 17)
                              + (size_t)lane * 16;

    i32x4 af0[2], af1[2], af2[2], af3[2], bfA[4], bfB[4];

    // --- prologue: stage B(0); prefetch af(ks0), af(ks1) --------------------
#pragma unroll
    for (int ks = 0; ks < 4; ++ks)
        gload_lds16(bSrc + ((size_t)ks << 10), BsF + ((wave * 4 + ks) << 10));
    FENCE;
    load_af(af0, aBase, 0);
    load_af(af1, aBase, 1);
    asm volatile("s_waitcnt vmcnt(4)" ::: "memory");   // B(0) done; af01 flying
    __builtin_amdgcn_s_barrier();

    // --- main K loop: 2 barrier-aligned phases per tile ---------------------
    for (int t = 0; t < NT; ++t) {
        const int8_t* bbuf = BsF + ((t & 1) << 14) + (size_t)lane * 16;
        int8_t* bstg = BsF + (((t + 1) & 1) << 14);
        const bool st = (t < NT - 1);

        // ---- phase 0: consume ks0,ks1; prefetch af(ks2,ks3); stage B(t+1) --
        load_bfl(bfA, bbuf, 0);
        load_bfl(bfB, bbuf, 1);
        FENCE;
        load_af(af2, aBase, t * 4 + 2);
        load_af(af3, aBase, t * 4 + 3);
        FENCE;
        if (st) {
#pragma unroll
            for (int ks = 0; ks < 4; ++ks)
                gload_lds16(bSrc + ((size_t)((t + 1) * 4 + ks) << 10),
                            bstg + ((wave * 4 + ks) << 10));
        }
        FENCE;
        __builtin_amdgcn_s_barrier();
        asm volatile("s_waitcnt lgkmcnt(0)" ::: "memory");
        __builtin_amdgcn_s_setprio(1);
        kkstep(af0, bfA, acc);
        kkstep(af1, bfB, acc);
        __builtin_amdgcn_s_setprio(0);
        __builtin_amdgcn_s_barrier();

        // ---- phase 1: consume ks2,ks3; prefetch af(t+1: ks0,ks1) -----------
        load_bfl(bfA, bbuf, 2);
        load_bfl(bfB, bbuf, 3);
        FENCE;
        load_af(af0, aBase, st ? (t + 1) * 4 : 0);       // clamped last tile
        load_af(af1, aBase, st ? (t + 1) * 4 + 1 : 1);
        FENCE;
        __builtin_amdgcn_s_barrier();
        asm volatile("s_waitcnt lgkmcnt(0)" ::: "memory");
        __builtin_amdgcn_s_setprio(1);
        kkstep(af2, bfA, acc);
        kkstep(af3, bfB, acc);
        __builtin_amdgcn_s_setprio(0);
        asm volatile("s_waitcnt vmcnt(4)" ::: "memory"); // staging retired
        __builtin_amdgcn_s_barrier();
    }

    // epilogue: 32x32 C/D layout: col = lane&31,
    // row = (reg&3) + 8*(reg>>2) + 4*(lane>>5)   [m74/m101, dtype-independent]
    int mymax = 0;
    const int ccol = fr;
    const int rbase = hl << 2;
#pragma unroll
    for (int i = 0; i < 2; ++i) {
#pragma unroll
        for (int j = 0; j < 4; ++j) {
            int* p = C + (size_t)(row0 + wm + i * 32) * N_DIM
                       + (col0 + j * 32 + ccol);
#pragma unroll
            for (int r = 0; r < 16; ++r) {
                int row = (r & 3) + 8 * (r >> 2) + rbase;
                int v = acc[i][j][r];
                p[(size_t)row * N_DIM] = v;
                int a = v < 0 ? -v : v;
                mymax = a > mymax ? a : mymax;
            }
        }
    }

    // wave-reduce max, then one atomic per block
#pragma unroll
    for (int off = 32; off > 0; off >>= 1) {
        int o = __shfl_down(mymax, off, 64);
        mymax = o > mymax ? o : mymax;
    }
    if (lane == 0) wmaxs[wave] = mymax;
    __syncthreads();
    if (tid == 0) {
        int bmx = wmaxs[0];
        for (int w = 1; w < 4; ++w) bmx = wmaxs[w] > bmx ? wmaxs[w] : bmx;
        atomicMax(maxabs, bmx);
    }
}

// ---------------------------------------------------------------------------
// Pseudo-stochastic shift, faithful to PstoShiftInt32 (all-integer, exact).
// ---------------------------------------------------------------------------
__device__ __forceinline__ int psto(int x, int eff) {
    if (eff > 0) {
        int rt   = x >> eff;                 // floor divide by 2^eff
        int prob = x & ((1 << eff) - 1);     // non-negative floor remainder
        int h    = eff >> 1;
        int qp   = prob >> h;
        int prn  = (prob & ((1 << h) - 1)) << (eff & 1);
        int sgn  = (x > 0) - (x < 0);
        int r    = rt + ((qp <= prn) ? 0 : sgn);
        r = r < -127 ? -127 : r;
        r = r > 127 ? 127 : r;
        return r;
    }
    return (int)(int8_t)x;                   // wrapping int8 cast, as in torch
}

// ---------------------------------------------------------------------------
// In-place: read int32 acc from C, write int32 quantized value back.
// ---------------------------------------------------------------------------
__global__ __launch_bounds__(256) void finalize_kernel(int* __restrict__ C,
        const int* __restrict__ maxabs,
        const int* __restrict__ exp_in,
        const int* __restrict__ wexp) {
    const int m = *maxabs;
    int bw = 0;
    if (m != 0) bw = (int)ceilf(log2f((float)m));   // float32 path, as reference
    const int shift = bw - BITWIDTH;
    const int eff = (shift > 1) ? shift : ((shift == 1) ? 2 : 0);

    const size_t idx = ((size_t)blockIdx.x * blockDim.x + threadIdx.x) * 8;
    int4 v0 = *(const int4*)(C + idx);
    int4 v1 = *(const int4*)(C + idx + 4);
    int4 o0, o1;
    o0.x = psto(v0.x, eff); o0.y = psto(v0.y, eff);
    o0.z = psto(v0.z, eff); o0.w = psto(v0.w, eff);
    o1.x = psto(v1.x, eff); o1.y = psto(v1.y, eff);
    o1.z = psto(v1.z, eff); o1.w = psto(v1.w, eff);
    *(int4*)(C + idx) = o0;
    *(int4*)(C + idx + 4) = o1;

    if (idx == 0) {
        C[(size_t)M_DIM * N_DIM] = (int)(int8_t)(exp_in[0] + wexp[0] + eff);
    }
}

// ---------------------------------------------------------------------------
extern "C" void kernel_launch(void* const* d_in, const int* in_sizes, int n_in,
                              void* d_out, int out_size, void* d_ws, size_t ws_size,
                              hipStream_t stream) {
    const int* act    = (const int*)d_in[0];
    const int* exp_in = (const int*)d_in[1];
    const int* wt     = (const int*)d_in[2];
    const int* wexp   = (const int*)d_in[3];

    int8_t* a8p    = (int8_t*)d_ws;                          // 32 MB (frag-packed)
    int8_t* w8p    = a8p + (size_t)M_DIM * K_DIM;            // 16 MB (frag-packed)
    int*    maxabs = (int*)(w8p + (size_t)N_DIM * K_DIM);    // 4 B

    // blocks [0,8192): A frag-pack; [8192,12288): B frag-pack
    pack_both_kernel<<<12288, 256, 0, stream>>>(
        act, wt, (uint32_t*)a8p, (uint32_t*)w8p, maxabs);

    int* C = (int*)d_out;    // acc staged in-place in d_out
    dim3 grid(N_DIM / BN, M_DIM / BM);
    gemm_i8<<<grid, 256, 0, stream>>>(a8p, w8p, C, maxabs);

    finalize_kernel<<<((size_t)M_DIM * N_DIM / 8) / 256, 256, 0, stream>>>(
        C, maxabs, exp_in, wexp);
}